// Round 15
// baseline (644.581 us; speedup 1.0000x reference)
//
#include <hip/hip_runtime.h>

typedef short bf16x8 __attribute__((ext_vector_type(8)));
typedef float f32x4 __attribute__((ext_vector_type(4)));
typedef unsigned int u32;
typedef unsigned short u16;

#define NIT 21
#define SMIN 1e-33f
#define LDSCOL 136   // padded row stride in u16 (272B, 16B-aligned)

static __device__ __forceinline__ u16 f2bf(float f) {   // RNE pack (validated r8/r14)
    u32 u = __float_as_uint(f);
    u = (u + 0x7fffu + ((u >> 16) & 1u)) >> 16;
    return (u16)u;
}
static __device__ __forceinline__ float bf2f(u16 h) {
    return __uint_as_float(((u32)h) << 16);
}

// MFMA Sinkhorn (r14 structure, validated): one 256-thread block per 128x128
// matrix; E = bf16(2^((x-m)*S)) as per-wave MFMA fragments af (rows, A-op) and
// bf (cols, B-op); each phase = 8 chained v_mfma_f32_16x16x32_bf16; a/b via
// 256B LDS. Round-15 (occupancy attack; r14 had 35KB LDS -> 3 blocks/CU, all
// pipes <35% busy): (1) E staged through ONE 32-row chunk buffer (8.7KB),
// chunk c written by wave c (it owns rows c*32..+31), two barriers per chunk;
// (2) two-pass init (rowmax pass, then volatile scalar reload + exp pass) so
// the 32-float v never coexists with the 64-reg fragment set; (3)
// waves_per_eu(5,5) pins the 102-reg budget -> 5 waves/SIMD, 5 blocks/CU.
// Tripwire: FETCH >200MB / dur regress = spill -> revert to (4,4).
__global__ void __attribute__((amdgpu_flat_work_group_size(256, 256),
                               amdgpu_waves_per_eu(5, 5)))
sinkhorn_kernel(const float* __restrict__ in, float* __restrict__ out) {
    const int t  = threadIdx.x;
    const int w  = t >> 6;         // wave 0..3
    const int lg = (t >> 4) & 3;   // k-group within wave
    const int ln = t & 15;         // m/n within tile
    const size_t mat = (size_t)blockIdx.x << 14;
    const float S = 36.067376022224085f;   // (1/0.04)*log2(e)

    __shared__ __align__(16) u16 E_stage[32 * LDSCOL];   // one 32-row chunk
    __shared__ __align__(16) u16 a_lds[128];
    __shared__ __align__(16) u16 b_lds[128];

    bf16x8 af[2][4];   // af[th][c] = E[w*32+th*16+ln][c*32+lg*8 ..+7]
    bf16x8 bf[2][4];   // bf[uh][c] = E[c*32+lg*8+j][w*32+uh*16+ln]

    // ---- init, two-pass: (1) rowmax; (2) reload + exp + pack; a = rcp(rowsum) ----
#pragma unroll
    for (int th = 0; th < 2; ++th) {
        const int M = w * 32 + th * 16 + ln;
        const float* src = in + mat + (size_t)M * 128 + lg * 8;
        float m = -3.4e38f;
#pragma unroll
        for (int c = 0; c < 4; ++c) {
            float4 f0 = *(const float4*)(src + c * 32);
            float4 f1 = *(const float4*)(src + c * 32 + 4);
            m = fmaxf(m, fmaxf(fmaxf(f0.x, f0.y), fmaxf(f0.z, f0.w)));
            m = fmaxf(m, fmaxf(fmaxf(f1.x, f1.y), fmaxf(f1.z, f1.w)));
        }
        // row M held by lanes {ln, ln+16, ln+32, ln+48}
        m = fmaxf(m, __shfl_xor(m, 16));
        m = fmaxf(m, __shfl_xor(m, 32));
        const float nms = -m * S;
        // pass 2: volatile scalar reload (blocks CSE back to pass-1 values; L2-hot)
        const volatile float* vsrc = (const volatile float*)src;
        float s = 0.f;
#pragma unroll
        for (int c = 0; c < 4; ++c) {
            bf16x8 fr;
#pragma unroll
            for (int j = 0; j < 8; ++j) {
                float e = __builtin_amdgcn_exp2f(fmaf(vsrc[c * 32 + j], S, nms));
                s += e;
                fr[j] = (short)f2bf(e);
            }
            af[th][c] = fr;
        }
        s += __shfl_xor(s, 16);
        s += __shfl_xor(s, 32);
        if (lg == 0) a_lds[M] = f2bf(__builtin_amdgcn_rcpf(fmaxf(s, SMIN)));
    }

    // ---- build bf via 4 staged chunks: chunk c = rows c*32..+31 (owned by wave c) ----
#pragma unroll 1
    for (int c = 0; c < 4; ++c) {
        if (w == c) {
#pragma unroll
            for (int th = 0; th < 2; ++th)
#pragma unroll
                for (int cc = 0; cc < 4; ++cc)
                    *(bf16x8*)&E_stage[(th * 16 + ln) * LDSCOL + cc * 32 + lg * 8] = af[th][cc];
        }
        __syncthreads();
#pragma unroll
        for (int uh = 0; uh < 2; ++uh) {
            const int N = w * 32 + uh * 16 + ln;
            bf16x8 fr;
#pragma unroll
            for (int j = 0; j < 8; ++j)
                fr[j] = (short)E_stage[(lg * 8 + j) * LDSCOL + N];
            bf[uh][c] = fr;
        }
        __syncthreads();
    }

    const f32x4 z4 = {0.f, 0.f, 0.f, 0.f};

#pragma unroll 1
    for (int it = 0; it < NIT; ++it) {
        // ---- col phase: colsum_n = sum_k a_k E_kn  (A = a replicated) ----
        f32x4 acc0 = z4, acc1 = z4;
#pragma unroll
        for (int c = 0; c < 4; ++c) {
            bf16x8 aop = *(const bf16x8*)&a_lds[c * 32 + lg * 8];
            acc0 = __builtin_amdgcn_mfma_f32_16x16x32_bf16(aop, bf[0][c], acc0, 0, 0, 0);
            acc1 = __builtin_amdgcn_mfma_f32_16x16x32_bf16(aop, bf[1][c], acc1, 0, 0, 0);
        }
        if (lg == 0) {   // D rows identical; lane holds col n=ln of its tile
            b_lds[w * 32 + ln]      = f2bf(__builtin_amdgcn_rcpf(fmaxf(acc0[0], SMIN)));
            b_lds[w * 32 + 16 + ln] = f2bf(__builtin_amdgcn_rcpf(fmaxf(acc1[0], SMIN)));
        }
        __syncthreads();

        // ---- row phase: rowsum_m = sum_k E_mk b_k  (B = b replicated) ----
        if (it < NIT - 1) {
            f32x4 r0 = z4, r1 = z4;
#pragma unroll
            for (int c = 0; c < 4; ++c) {
                bf16x8 bop = *(const bf16x8*)&b_lds[c * 32 + lg * 8];
                r0 = __builtin_amdgcn_mfma_f32_16x16x32_bf16(af[0][c], bop, r0, 0, 0, 0);
                r1 = __builtin_amdgcn_mfma_f32_16x16x32_bf16(af[1][c], bop, r1, 0, 0, 0);
            }
            if (ln == 0) {   // D cols identical; lane holds rows lg*4+reg
#pragma unroll
                for (int r = 0; r < 4; ++r) {
                    a_lds[w * 32 +      lg * 4 + r] = f2bf(__builtin_amdgcn_rcpf(fmaxf(r0[r], SMIN)));
                    a_lds[w * 32 + 16 + lg * 4 + r] = f2bf(__builtin_amdgcn_rcpf(fmaxf(r1[r], SMIN)));
                }
            }
            __syncthreads();
        }
    }

    // ---- epilogue: out = E * a_m * b_n ----
#pragma unroll
    for (int th = 0; th < 2; ++th) {
        const int M = w * 32 + th * 16 + ln;
        float* dst = out + mat + (size_t)M * 128 + lg * 8;
        const float av = bf2f(a_lds[M]);
#pragma unroll
        for (int c = 0; c < 4; ++c) {
            const bf16x8 e = af[th][c];
            const bf16x8 bop = *(const bf16x8*)&b_lds[c * 32 + lg * 8];
            float4 o0, o1;
            o0.x = bf2f((u16)e[0]) * av * bf2f((u16)bop[0]);
            o0.y = bf2f((u16)e[1]) * av * bf2f((u16)bop[1]);
            o0.z = bf2f((u16)e[2]) * av * bf2f((u16)bop[2]);
            o0.w = bf2f((u16)e[3]) * av * bf2f((u16)bop[3]);
            o1.x = bf2f((u16)e[4]) * av * bf2f((u16)bop[4]);
            o1.y = bf2f((u16)e[5]) * av * bf2f((u16)bop[5]);
            o1.z = bf2f((u16)e[6]) * av * bf2f((u16)bop[6]);
            o1.w = bf2f((u16)e[7]) * av * bf2f((u16)bop[7]);
            *(float4*)(dst + c * 32)     = o0;
            *(float4*)(dst + c * 32 + 4) = o1;
        }
    }
}

extern "C" void kernel_launch(void* const* d_in, const int* in_sizes, int n_in,
                              void* d_out, int out_size, void* d_ws, size_t ws_size,
                              hipStream_t stream) {
    (void)n_in; (void)d_ws; (void)ws_size; (void)out_size;
    const float* in  = (const float*)d_in[0];
    float*       out = (float*)d_out;
    const int n_mat = in_sizes[0] / (128 * 128);  // 4096
    sinkhorn_kernel<<<dim3(n_mat), dim3(256), 0, stream>>>(in, out);
}

// Round 16
// 153.360 us; speedup vs baseline: 4.2031x; 4.2031x over previous
//
#include <hip/hip_runtime.h>

typedef short bf16x8 __attribute__((ext_vector_type(8)));
typedef float f32x4 __attribute__((ext_vector_type(4)));
typedef unsigned int u32;
typedef unsigned short u16;

#define NIT 21
#define SMIN 1e-33f
#define LDSCOL 136   // padded k-stride in u16 (272B: 16B-aligned, odd dword count spreads banks)

static __device__ __forceinline__ u16 f2bf(float f) {   // RNE pack (validated r8/r14)
    u32 u = __float_as_uint(f);
    u = (u + 0x7fffu + ((u >> 16) & 1u)) >> 16;
    return (u16)u;
}
static __device__ __forceinline__ float bf2f(u16 h) {
    return __uint_as_float(((u32)h) << 16);
}

// MFMA Sinkhorn (r14 loop, validated). One 256-thread block per 128x128
// matrix. Row fragments af (A-operand) in registers; col fragments (B-operand)
// read per-iteration from an E^T image in LDS (Ecm[n][k], one ds_read_b128
// per fragment - same bytes r14's bf held in AGPRs). This drops unified regs
// ~156 -> ~124/wave -> 4 waves/SIMD (r14 was 3; its occupancy 21% / all pipes
// <35% busy was the whole problem). waves_per_eu(4,4) pins the 128 budget
// (proven spill-free at this footprint in r12; r11/r13/r15 show caps below
// footprint spill -> FETCH tripwire). Phases: colsum/rowsum as chained
// v_mfma_f32_16x16x32_bf16; a/b vectors in 256B LDS; both operands of every
// mfma use the same (lane,slot)->k map so HW k-permutation cancels.
__global__ void __attribute__((amdgpu_flat_work_group_size(256, 256),
                               amdgpu_waves_per_eu(4, 4)))
sinkhorn_kernel(const float* __restrict__ in, float* __restrict__ out) {
    const int t  = threadIdx.x;
    const int w  = t >> 6;         // wave 0..3
    const int lg = (t >> 4) & 3;   // k-group within wave
    const int ln = t & 15;         // m/n within tile
    const size_t mat = (size_t)blockIdx.x << 14;
    const float S = 36.067376022224085f;   // (1/0.04)*log2(e)

    __shared__ __align__(16) u16 Ecm[128 * LDSCOL];   // E^T: Ecm[n*LDSCOL+k] = E[k][n]
    __shared__ __align__(16) u16 a_lds[128];
    __shared__ __align__(16) u16 b_lds[128];

    bf16x8 af[2][4];   // af[th][c] = E[w*32+th*16+ln][c*32+lg*8 ..+7]

    // ---- init: load, rowmax, E = bf16(2^((x-m)*S)); af regs + transposed LDS image ----
#pragma unroll
    for (int th = 0; th < 2; ++th) {
        const int M = w * 32 + th * 16 + ln;
        const float* src = in + mat + (size_t)M * 128 + lg * 8;
        float v[4][8];
        float m = -3.4e38f;
#pragma unroll
        for (int c = 0; c < 4; ++c) {
            float4 f0 = *(const float4*)(src + c * 32);
            float4 f1 = *(const float4*)(src + c * 32 + 4);
            v[c][0] = f0.x; v[c][1] = f0.y; v[c][2] = f0.z; v[c][3] = f0.w;
            v[c][4] = f1.x; v[c][5] = f1.y; v[c][6] = f1.z; v[c][7] = f1.w;
#pragma unroll
            for (int j = 0; j < 8; ++j) m = fmaxf(m, v[c][j]);
        }
        m = fmaxf(m, __shfl_xor(m, 16));   // row M held by lanes {ln,+16,+32,+48}
        m = fmaxf(m, __shfl_xor(m, 32));
        const float nms = -m * S;
        float s = 0.f;
#pragma unroll
        for (int c = 0; c < 4; ++c) {
            bf16x8 fr;
#pragma unroll
            for (int j = 0; j < 8; ++j) {
                float e = __builtin_amdgcn_exp2f(fmaf(v[c][j], S, nms));
                s += e;
                fr[j] = (short)f2bf(e);
            }
            af[th][c] = fr;
#pragma unroll
            for (int j = 0; j < 8; ++j)     // transposed scalar writes (one-time)
                Ecm[(c * 32 + lg * 8 + j) * LDSCOL + M] = (u16)fr[j];
        }
        s += __shfl_xor(s, 16);
        s += __shfl_xor(s, 32);
        if (lg == 0) a_lds[M] = f2bf(__builtin_amdgcn_rcpf(fmaxf(s, SMIN)));  // rowsum in [1,128]
    }
    __syncthreads();

    const f32x4 z4 = {0.f, 0.f, 0.f, 0.f};

#pragma unroll 1
    for (int it = 0; it < NIT; ++it) {
        // ---- col phase: colsum_n = sum_k a_k E_kn (A = a replicated; B from Ecm) ----
        f32x4 acc0 = z4, acc1 = z4;
        const int N0 = w * 32 + ln;        // wait: B-lane n = ln; tile uh adds 16
#pragma unroll
        for (int c = 0; c < 4; ++c) {
            bf16x8 aop = *(const bf16x8*)&a_lds[c * 32 + lg * 8];
            bf16x8 b0  = *(const bf16x8*)&Ecm[N0 * LDSCOL + c * 32 + lg * 8];
            bf16x8 b1  = *(const bf16x8*)&Ecm[(N0 + 16) * LDSCOL + c * 32 + lg * 8];
            acc0 = __builtin_amdgcn_mfma_f32_16x16x32_bf16(aop, b0, acc0, 0, 0, 0);
            acc1 = __builtin_amdgcn_mfma_f32_16x16x32_bf16(aop, b1, acc1, 0, 0, 0);
        }
        if (lg == 0) {   // D rows identical; lane holds col n=ln of its tile (m89 layout)
            b_lds[w * 32 + ln]      = f2bf(__builtin_amdgcn_rcpf(fmaxf(acc0[0], SMIN)));
            b_lds[w * 32 + 16 + ln] = f2bf(__builtin_amdgcn_rcpf(fmaxf(acc1[0], SMIN)));
        }
        __syncthreads();

        // ---- row phase: rowsum_m = sum_k E_mk b_k  (B = b replicated) ----
        if (it < NIT - 1) {
            f32x4 r0 = z4, r1 = z4;
#pragma unroll
            for (int c = 0; c < 4; ++c) {
                bf16x8 bop = *(const bf16x8*)&b_lds[c * 32 + lg * 8];
                r0 = __builtin_amdgcn_mfma_f32_16x16x32_bf16(af[0][c], bop, r0, 0, 0, 0);
                r1 = __builtin_amdgcn_mfma_f32_16x16x32_bf16(af[1][c], bop, r1, 0, 0, 0);
            }
            if (ln == 0) {   // D cols identical; lane holds rows lg*4+reg
#pragma unroll
                for (int r = 0; r < 4; ++r) {
                    a_lds[w * 32 +      lg * 4 + r] = f2bf(__builtin_amdgcn_rcpf(fmaxf(r0[r], SMIN)));
                    a_lds[w * 32 + 16 + lg * 4 + r] = f2bf(__builtin_amdgcn_rcpf(fmaxf(r1[r], SMIN)));
                }
            }
            __syncthreads();
        }
    }

    // ---- epilogue: out = E * a_m * b_n ----
#pragma unroll
    for (int th = 0; th < 2; ++th) {
        const int M = w * 32 + th * 16 + ln;
        float* dst = out + mat + (size_t)M * 128 + lg * 8;
        const float av = bf2f(a_lds[M]);
#pragma unroll
        for (int c = 0; c < 4; ++c) {
            const bf16x8 e = af[th][c];
            const bf16x8 bop = *(const bf16x8*)&b_lds[c * 32 + lg * 8];
            float4 o0, o1;
            o0.x = bf2f((u16)e[0]) * av * bf2f((u16)bop[0]);
            o0.y = bf2f((u16)e[1]) * av * bf2f((u16)bop[1]);
            o0.z = bf2f((u16)e[2]) * av * bf2f((u16)bop[2]);
            o0.w = bf2f((u16)e[3]) * av * bf2f((u16)bop[3]);
            o1.x = bf2f((u16)e[4]) * av * bf2f((u16)bop[4]);
            o1.y = bf2f((u16)e[5]) * av * bf2f((u16)bop[5]);
            o1.z = bf2f((u16)e[6]) * av * bf2f((u16)bop[6]);
            o1.w = bf2f((u16)e[7]) * av * bf2f((u16)bop[7]);
            *(float4*)(dst + c * 32)     = o0;
            *(float4*)(dst + c * 32 + 4) = o1;
        }
    }
}

extern "C" void kernel_launch(void* const* d_in, const int* in_sizes, int n_in,
                              void* d_out, int out_size, void* d_ws, size_t ws_size,
                              hipStream_t stream) {
    (void)n_in; (void)d_ws; (void)ws_size; (void)out_size;
    const float* in  = (const float*)d_in[0];
    float*       out = (float*)d_out;
    const int n_mat = in_sizes[0] / (128 * 128);  // 4096
    sinkhorn_kernel<<<dim3(n_mat), dim3(256), 0, stream>>>(in, out);
}